// Round 1
// baseline (808.500 us; speedup 1.0000x reference)
//
#include <hip/hip_runtime.h>

// XConv: N=16, P=1024, K=16, D=3, Cf=64, Fin=64, Ccat=128, DM=4, Cout=128
// NP = 16384 points total.
//
// ws layout (floats):
//   X3  : [16384][256]  (16 MB)
//   dwf : [16384][512]  (32 MB)
//   y   : [16384][128]  (8 MB)
//   st  : scale[128], shift[128]

#define NPTS 16384

// ---------------- Kernel A: X-transform chain ----------------
// 16 points per block, 256 threads. thread o owns output feature o.
__global__ __launch_bounds__(256) void kA_xchain(
    const float* __restrict__ rep, const float* __restrict__ pts,
    const float* __restrict__ Wxc, const float* __restrict__ bxc,
    const float* __restrict__ Wx1, const float* __restrict__ bx1,
    const float* __restrict__ Wx2, const float* __restrict__ bx2,
    float* __restrict__ X3out)
{
    __shared__ __align__(16) float ptsl[16][48];   // [pt][d*16+k]
    __shared__ __align__(16) float X1[16][256];
    __shared__ __align__(16) float X2[16][256];
    const int tid = threadIdx.x;
    const int base = blockIdx.x * 16;

    for (int idx = tid; idx < 16*48; idx += 256) {
        int pt = idx / 48, j = idx - pt*48;
        int d = j >> 4, k = j & 15;
        int q = base + pt;
        ptsl[pt][j] = pts[(q*16 + k)*3 + d] - rep[q*3 + d];
    }
    __syncthreads();

    // X1[pt][o] = relu(b + sum_j Wxc[o][j]*ptsl[pt][j]), j = d*16+k
    {
        const int o = tid;
        float w[48];
        #pragma unroll
        for (int j = 0; j < 48; j += 4)
            *(float4*)&w[j] = *(const float4*)(Wxc + o*48 + j);
        const float b = bxc[o];
        for (int pt = 0; pt < 16; ++pt) {
            float acc = b;
            #pragma unroll
            for (int j = 0; j < 48; ++j) acc += w[j]*ptsl[pt][j];
            X1[pt][o] = fmaxf(acc, 0.f);
        }
    }
    __syncthreads();

    // X2[pt][o] = relu(b + sum_j Wx1[o][j]*X1[pt][j])
    {
        const int o = tid;
        float acc[16];
        const float b = bx1[o];
        #pragma unroll
        for (int pt = 0; pt < 16; ++pt) acc[pt] = b;
        for (int j0 = 0; j0 < 256; j0 += 8) {
            float4 wa = *(const float4*)(Wx1 + o*256 + j0);
            float4 wb = *(const float4*)(Wx1 + o*256 + j0 + 4);
            #pragma unroll
            for (int pt = 0; pt < 16; ++pt) {
                float4 xa = *(const float4*)&X1[pt][j0];
                float4 xb = *(const float4*)&X1[pt][j0+4];
                acc[pt] += wa.x*xa.x + wa.y*xa.y + wa.z*xa.z + wa.w*xa.w
                         + wb.x*xb.x + wb.y*xb.y + wb.z*xb.z + wb.w*xb.w;
            }
        }
        #pragma unroll
        for (int pt = 0; pt < 16; ++pt) X2[pt][o] = fmaxf(acc[pt], 0.f);
    }
    __syncthreads();

    // X3[pt][o] = b + sum_j Wx2[o][j]*X2[pt][j]   (no relu) -> global
    {
        const int o = tid;
        float acc[16];
        const float b = bx2[o];
        #pragma unroll
        for (int pt = 0; pt < 16; ++pt) acc[pt] = b;
        for (int j0 = 0; j0 < 256; j0 += 8) {
            float4 wa = *(const float4*)(Wx2 + o*256 + j0);
            float4 wb = *(const float4*)(Wx2 + o*256 + j0 + 4);
            #pragma unroll
            for (int pt = 0; pt < 16; ++pt) {
                float4 xa = *(const float4*)&X2[pt][j0];
                float4 xb = *(const float4*)&X2[pt][j0+4];
                acc[pt] += wa.x*xa.x + wa.y*xa.y + wa.z*xa.z + wa.w*xa.w
                         + wb.x*xb.x + wb.y*xb.y + wb.z*xb.z + wb.w*xb.w;
            }
        }
        for (int pt = 0; pt < 16; ++pt)
            X3out[(size_t)(base+pt)*256 + o] = acc[pt];
    }
}

// ---------------- Kernel B: lift + concat + fts_X + depthwise ----------------
// 4 points per block = 64 rows (pt*16+k), 256 threads = 64 rows x 4 col-groups.
__global__ __launch_bounds__(256) void kB_feat(
    const float* __restrict__ rep, const float* __restrict__ pts,
    const float* __restrict__ fts,
    const float* __restrict__ Wf1, const float* __restrict__ bf1,
    const float* __restrict__ Wf2, const float* __restrict__ bf2,
    const float* __restrict__ Wdw, const float* __restrict__ bdw,
    const float* __restrict__ X3in, float* __restrict__ dwout)
{
    __shared__ __align__(16) float ptsl2[64*3];
    __shared__ __align__(16) float W1s[64*3];
    __shared__ __align__(16) float b1s[64];
    __shared__ __align__(16) float b2s[64];
    __shared__ __align__(16) float fcat[64][128];
    __shared__ __align__(16) float X3l[4][256];
    __shared__ __align__(16) float fX[64][128];

    const int tid = threadIdx.x;
    const int base4 = blockIdx.x * 4;

    // phase 0: stage small tensors
    for (int idx = tid; idx < 192; idx += 256) {
        int r = idx / 3, d = idx - r*3;
        int pt = r >> 4, k = r & 15;
        int q = base4 + pt;
        ptsl2[idx] = pts[(q*16 + k)*3 + d] - rep[q*3 + d];
        W1s[idx] = Wf1[idx];
    }
    if (tid < 64) { b1s[tid] = bf1[tid]; b2s[tid] = bf2[tid]; }
    __syncthreads();

    const int r = tid >> 2, cg = tid & 3;

    // phase 1: FC1 (into regs) + FC2 -> fcat[r][0..64)
    {
        float x0 = ptsl2[r*3+0], x1 = ptsl2[r*3+1], x2 = ptsl2[r*3+2];
        float h[64];
        #pragma unroll
        for (int f = 0; f < 64; ++f)
            h[f] = fmaxf(b1s[f] + W1s[f*3]*x0 + W1s[f*3+1]*x1 + W1s[f*3+2]*x2, 0.f);
        for (int gi = 0; gi < 16; ++gi) {
            int g = cg*16 + gi;
            float acc = b2s[g];
            #pragma unroll
            for (int f0 = 0; f0 < 64; f0 += 4) {
                float4 w = *(const float4*)(Wf2 + g*64 + f0);
                acc += h[f0]*w.x + h[f0+1]*w.y + h[f0+2]*w.z + h[f0+3]*w.w;
            }
            fcat[r][g] = fmaxf(acc, 0.f);
        }
    }

    // phase 2: load fts -> fcat[r][64..128).  Global chunk is contiguous:
    // flat = (base4*16 + r)*64 + c = base4*1024 + r*64 + c
    for (int t = tid; t < 1024; t += 256) {
        int rr = t >> 4, c4 = (t & 15) << 2;
        *(float4*)&fcat[rr][64 + c4] =
            *(const float4*)(fts + (size_t)base4*1024 + rr*64 + c4);
    }

    // phase 3: load X3 tile
    {
        ((float4*)&X3l[0][0])[tid] = ((const float4*)(X3in + (size_t)base4*256))[tid];
    }
    __syncthreads();

    // phase 4: fts_X[r][c] = sum_j X3[pt][i*16+j] * fcat[pt*16+j][c]
    {
        const int pt = r >> 4, i = r & 15;
        float xrow[16];
        #pragma unroll
        for (int jj = 0; jj < 16; jj += 4)
            *(float4*)&xrow[jj] = *(const float4*)&X3l[pt][i*16 + jj];
        float acc[32];
        #pragma unroll
        for (int a = 0; a < 32; ++a) acc[a] = 0.f;
        #pragma unroll
        for (int j = 0; j < 16; ++j) {
            float xv = xrow[j];
            int row = pt*16 + j;
            #pragma unroll
            for (int t = 0; t < 8; ++t) {   // c = cg*4 + t*16 (+0..3): conflict-free
                float4 v = *(const float4*)&fcat[row][cg*4 + t*16];
                acc[t*4+0] += xv*v.x; acc[t*4+1] += xv*v.y;
                acc[t*4+2] += xv*v.z; acc[t*4+3] += xv*v.w;
            }
        }
        #pragma unroll
        for (int t = 0; t < 8; ++t) {
            float4 v = make_float4(acc[t*4+0], acc[t*4+1], acc[t*4+2], acc[t*4+3]);
            *(float4*)&fX[r][cg*4 + t*16] = v;
        }
    }
    __syncthreads();

    // phase 5: depthwise.  dw[pt][c*4+m] = b_dw + sum_k fX[pt*16+k][c]*Wdw[c][m][k]
    for (int iter = 0; iter < 8; ++iter) {
        int t = tid + iter*256;
        int pt = t >> 9, rest = t & 511;
        int c = rest >> 2;
        float wv[16];
        #pragma unroll
        for (int kk = 0; kk < 16; kk += 4)
            *(float4*)&wv[kk] = *(const float4*)(Wdw + rest*16 + kk);
        float acc = bdw[rest];
        #pragma unroll
        for (int k = 0; k < 16; ++k) acc += fX[pt*16 + k][c] * wv[k];
        dwout[(size_t)base4*512 + t] = acc;
    }
}

// ---------------- Kernel C: pointwise GEMM ----------------
// y[q][o] = b_pw[o] + sum_j dwf[q][j]*Wpw[o][j].  64 points/block.
__global__ __launch_bounds__(256) void kC_pw(
    const float* __restrict__ dwf, const float* __restrict__ Wpw,
    const float* __restrict__ bpw, float* __restrict__ yout)
{
    __shared__ __align__(16) float dtile[64][128];
    const int tid = threadIdx.x;
    const int o = tid & 127;
    const int ptg = tid >> 7;
    const int base = blockIdx.x * 64;
    float acc[32];
    #pragma unroll
    for (int i = 0; i < 32; ++i) acc[i] = 0.f;

    for (int ch = 0; ch < 4; ++ch) {
        __syncthreads();
        for (int t = tid; t < 64*32; t += 256) {
            int row = t >> 5, c4 = (t & 31) << 2;
            *(float4*)&dtile[row][c4] =
                *(const float4*)(dwf + (size_t)(base+row)*512 + ch*128 + c4);
        }
        __syncthreads();
        for (int j0 = 0; j0 < 128; j0 += 4) {
            float4 w = *(const float4*)(Wpw + (size_t)o*512 + ch*128 + j0);
            #pragma unroll
            for (int pt = 0; pt < 32; ++pt) {
                float4 d = *(const float4*)&dtile[ptg*32 + pt][j0];
                acc[pt] += w.x*d.x + w.y*d.y + w.z*d.z + w.w*d.w;
            }
        }
    }
    const float b = bpw[o];
    for (int pt = 0; pt < 32; ++pt)
        yout[(size_t)(base + ptg*32 + pt)*128 + o] = acc[pt] + b;
}

// ---------------- Kernel D: BN stats -> scale/shift ----------------
__global__ __launch_bounds__(256) void kD_stats(
    const float* __restrict__ y, const float* __restrict__ gamma,
    const float* __restrict__ beta, float* __restrict__ st)
{
    const int c = blockIdx.x, tid = threadIdx.x;
    float s = 0.f, s2 = 0.f;
    for (int q = tid; q < NPTS; q += 256) {
        float v = y[(size_t)q*128 + c];
        s += v; s2 += v*v;
    }
    __shared__ float sb[256], s2b[256];
    sb[tid] = s; s2b[tid] = s2;
    __syncthreads();
    for (int off = 128; off > 0; off >>= 1) {
        if (tid < off) { sb[tid] += sb[tid+off]; s2b[tid] += s2b[tid+off]; }
        __syncthreads();
    }
    if (tid == 0) {
        float mean = sb[0] * (1.f/NPTS);
        float var  = s2b[0] * (1.f/NPTS) - mean*mean;
        float rstd = rsqrtf(var + 1e-5f);
        float scale = gamma[c] * rstd;
        st[c] = scale;
        st[128 + c] = beta[c] - mean*scale;
    }
}

// ---------------- Kernel E: normalize + relu ----------------
__global__ __launch_bounds__(256) void kE_final(
    const float* __restrict__ y, const float* __restrict__ st,
    float* __restrict__ out)
{
    const int idx = blockIdx.x*256 + threadIdx.x;   // float4 index
    float4 v = ((const float4*)y)[idx];
    int o0 = (idx & 31) << 2;
    float4 sc = *(const float4*)(st + o0);
    float4 sh = *(const float4*)(st + 128 + o0);
    float4 r;
    r.x = fmaxf(v.x*sc.x + sh.x, 0.f);
    r.y = fmaxf(v.y*sc.y + sh.y, 0.f);
    r.z = fmaxf(v.z*sc.z + sh.z, 0.f);
    r.w = fmaxf(v.w*sc.w + sh.w, 0.f);
    ((float4*)out)[idx] = r;
}

extern "C" void kernel_launch(void* const* d_in, const int* in_sizes, int n_in,
                              void* d_out, int out_size, void* d_ws, size_t ws_size,
                              hipStream_t stream) {
    const float* rep  = (const float*)d_in[0];
    const float* pts  = (const float*)d_in[1];
    const float* fts  = (const float*)d_in[2];
    const float* Wf1  = (const float*)d_in[3];
    const float* bf1  = (const float*)d_in[4];
    const float* Wf2  = (const float*)d_in[5];
    const float* bf2  = (const float*)d_in[6];
    const float* Wxc  = (const float*)d_in[7];
    const float* bxc  = (const float*)d_in[8];
    const float* Wx1  = (const float*)d_in[9];
    const float* bx1  = (const float*)d_in[10];
    const float* Wx2  = (const float*)d_in[11];
    const float* bx2  = (const float*)d_in[12];
    const float* Wdw  = (const float*)d_in[13];
    const float* bdw  = (const float*)d_in[14];
    const float* Wpw  = (const float*)d_in[15];
    const float* bpw  = (const float*)d_in[16];
    const float* gam  = (const float*)d_in[17];
    const float* bet  = (const float*)d_in[18];

    float* ws  = (float*)d_ws;
    float* X3  = ws;                                  // 16384*256
    float* dwf = X3 + (size_t)NPTS*256;               // 16384*512
    float* y   = dwf + (size_t)NPTS*512;              // 16384*128
    float* st  = y + (size_t)NPTS*128;                // 256

    kA_xchain<<<NPTS/16, 256, 0, stream>>>(rep, pts, Wxc, bxc, Wx1, bx1, Wx2, bx2, X3);
    kB_feat<<<NPTS/4, 256, 0, stream>>>(rep, pts, fts, Wf1, bf1, Wf2, bf2, Wdw, bdw, X3, dwf);
    kC_pw<<<NPTS/64, 256, 0, stream>>>(dwf, Wpw, bpw, y);
    kD_stats<<<128, 256, 0, stream>>>(y, gam, bet, st);
    kE_final<<<(NPTS*128/4)/256, 256, 0, stream>>>(y, st, (float*)d_out);
}

// Round 2
// 333.223 us; speedup vs baseline: 2.4263x; 2.4263x over previous
//
#include <hip/hip_runtime.h>

// XConv: N=16, P=1024, K=16, D=3, Cf=64, Fin=64, Ccat=128, DM=4, Cout=128
// NPTS = 16384 representative points; 262144 (point,k) rows.
//
// ws layout (floats):
//   X3  : [16384][256]  (16 MB)
//   dwf : [16384][512]  (32 MB)
//   y   : [16384][128]  (8 MB)
//   st  : scale[128], shift[128]
//   acc : accS[128], accS2[128]   (zeroed by kZ each launch)

#define NPTS 16384

// ---------------- Kernel A: X-transform chain ----------------
// 16 points per block, 256 threads. thread o owns output feature o.
__global__ __launch_bounds__(256) void kA_xchain(
    const float* __restrict__ rep, const float* __restrict__ pts,
    const float* __restrict__ Wxc, const float* __restrict__ bxc,
    const float* __restrict__ Wx1, const float* __restrict__ bx1,
    const float* __restrict__ Wx2, const float* __restrict__ bx2,
    float* __restrict__ X3out)
{
    __shared__ __align__(16) float ptsl[16][48];   // [pt][d*16+k]
    __shared__ __align__(16) float X1[16][256];
    __shared__ __align__(16) float X2[16][256];
    const int tid = threadIdx.x;
    const int base = blockIdx.x * 16;

    for (int idx = tid; idx < 16*48; idx += 256) {
        int pt = idx / 48, j = idx - pt*48;
        int d = j >> 4, k = j & 15;
        int q = base + pt;
        ptsl[pt][j] = pts[(q*16 + k)*3 + d] - rep[q*3 + d];
    }
    __syncthreads();

    {   // X1[pt][o] = relu(b + sum_j Wxc[o][j]*ptsl[pt][j])
        const int o = tid;
        float w[48];
        #pragma unroll
        for (int j = 0; j < 48; j += 4)
            *(float4*)&w[j] = *(const float4*)(Wxc + o*48 + j);
        const float b = bxc[o];
        #pragma unroll 4
        for (int pt = 0; pt < 16; ++pt) {
            float acc = b;
            #pragma unroll
            for (int j = 0; j < 48; ++j) acc += w[j]*ptsl[pt][j];
            X1[pt][o] = fmaxf(acc, 0.f);
        }
    }
    __syncthreads();

    {   // X2[pt][o] = relu(b + Wx1[o][:] . X1[pt][:])
        const int o = tid;
        float acc[16];
        const float b = bx1[o];
        #pragma unroll
        for (int pt = 0; pt < 16; ++pt) acc[pt] = b;
        #pragma unroll 4
        for (int j0 = 0; j0 < 256; j0 += 8) {
            float4 wa = *(const float4*)(Wx1 + o*256 + j0);
            float4 wb = *(const float4*)(Wx1 + o*256 + j0 + 4);
            #pragma unroll
            for (int pt = 0; pt < 16; ++pt) {
                float4 xa = *(const float4*)&X1[pt][j0];
                float4 xb = *(const float4*)&X1[pt][j0+4];
                acc[pt] += wa.x*xa.x + wa.y*xa.y + wa.z*xa.z + wa.w*xa.w
                         + wb.x*xb.x + wb.y*xb.y + wb.z*xb.z + wb.w*xb.w;
            }
        }
        #pragma unroll
        for (int pt = 0; pt < 16; ++pt) X2[pt][o] = fmaxf(acc[pt], 0.f);
    }
    __syncthreads();

    {   // X3[pt][o] = b + Wx2[o][:] . X2[pt][:]   (linear) -> global
        const int o = tid;
        float acc[16];
        const float b = bx2[o];
        #pragma unroll
        for (int pt = 0; pt < 16; ++pt) acc[pt] = b;
        #pragma unroll 4
        for (int j0 = 0; j0 < 256; j0 += 8) {
            float4 wa = *(const float4*)(Wx2 + o*256 + j0);
            float4 wb = *(const float4*)(Wx2 + o*256 + j0 + 4);
            #pragma unroll
            for (int pt = 0; pt < 16; ++pt) {
                float4 xa = *(const float4*)&X2[pt][j0];
                float4 xb = *(const float4*)&X2[pt][j0+4];
                acc[pt] += wa.x*xa.x + wa.y*xa.y + wa.z*xa.z + wa.w*xa.w
                         + wb.x*xb.x + wb.y*xb.y + wb.z*xb.z + wb.w*xb.w;
            }
        }
        for (int pt = 0; pt < 16; ++pt)
            X3out[(size_t)(base+pt)*256 + o] = acc[pt];
    }
}

// ---------------- Kernel B (fused): lift + concat + fts_X + depthwise ----------------
// 2 points per block = 32 rows, 256 threads. Wf2 in padded LDS; fcat padded
// [32][132] (bank drift 4/row -> conflict-free fX column reads); fX overlays fcat.
__global__ __launch_bounds__(256) void kB_fused(
    const float* __restrict__ rep, const float* __restrict__ pts,
    const float* __restrict__ fts,
    const float* __restrict__ Wf1, const float* __restrict__ bf1,
    const float* __restrict__ Wf2, const float* __restrict__ bf2,
    const float* __restrict__ Wdw, const float* __restrict__ bdw,
    const float* __restrict__ X3in, float* __restrict__ dwout)
{
    __shared__ __align__(16) float W2s[64][68];    // 17.4 KB, pad 4 -> conflict-free
    __shared__ __align__(16) float fcat[32][132];  // 16.9 KB, later overlaid with fX
    __shared__ __align__(16) float X3l[2][256];    // 2 KB
    __shared__ __align__(16) float W1s[64][4];     // 1 KB
    __shared__ __align__(16) float ptsl[32][4];
    __shared__ float b1s[64], b2s[64];

    const int tid = threadIdx.x;
    const int pbase = blockIdx.x * 2;          // first point of this block
    const int rbase = pbase * 16;              // first global row

    // ---- stage ----
    #pragma unroll
    for (int it = 0; it < 4; ++it) {           // W2s: 1024 float4, coalesced
        int idx = tid + it*256;
        int g = idx >> 4, f4 = (idx & 15) << 2;
        *(float4*)&W2s[g][f4] = *(const float4*)(Wf2 + g*64 + f4);
    }
    #pragma unroll
    for (int it = 0; it < 2; ++it) {           // fts -> fcat[:,64..128): 512 f4
        int idx = tid + it*256;
        int rr = idx >> 4, c4 = (idx & 15) << 2;
        *(float4*)&fcat[rr][64 + c4] = *(const float4*)(fts + (size_t)rbase*64 + idx*4);
    }
    if (tid < 128)                             // X3 tile: 512 floats
        ((float4*)&X3l[0][0])[tid] = ((const float4*)(X3in + (size_t)pbase*256))[tid];
    if (tid < 96) {                            // local coords
        int r = tid / 3, d = tid - r*3;
        int row = rbase + r, q = row >> 4;
        ptsl[r][d] = pts[(size_t)row*3 + d] - rep[q*3 + d];
    }
    if (tid >= 128 && tid < 192) {             // W1 + biases
        int f = tid - 128;
        W1s[f][0] = Wf1[f*3+0]; W1s[f][1] = Wf1[f*3+1];
        W1s[f][2] = Wf1[f*3+2]; W1s[f][3] = 0.f;
        b1s[f] = bf1[f]; b2s[f] = bf2[f];
    }
    __syncthreads();

    // ---- lift: FC1 (redundant x8) + FC2 -> fcat[:,0..64) ----
    {
        const int r = tid >> 3, og = tid & 7;  // thread owns outs {og, og+8, ...}
        float x0 = ptsl[r][0], x1 = ptsl[r][1], x2 = ptsl[r][2];
        float h[64];
        #pragma unroll
        for (int f = 0; f < 64; ++f) {
            float4 w = *(const float4*)&W1s[f][0];
            h[f] = fmaxf(b1s[f] + w.x*x0 + w.y*x1 + w.z*x2, 0.f);
        }
        #pragma unroll
        for (int k = 0; k < 8; ++k) {
            int g = og + k*8;
            float a0=0.f, a1=0.f, a2=0.f, a3=0.f;
            #pragma unroll
            for (int fq = 0; fq < 4; ++fq) {
                const float* wp = &W2s[g][fq*16];
                float4 wA = *(const float4*)(wp + 0);
                float4 wB = *(const float4*)(wp + 4);
                float4 wC = *(const float4*)(wp + 8);
                float4 wD = *(const float4*)(wp + 12);
                const float* hp = &h[fq*16];
                a0 += hp[0]*wA.x + hp[1]*wA.y + hp[2]*wA.z + hp[3]*wA.w;
                a1 += hp[4]*wB.x + hp[5]*wB.y + hp[6]*wB.z + hp[7]*wB.w;
                a2 += hp[8]*wC.x + hp[9]*wC.y + hp[10]*wC.z + hp[11]*wC.w;
                a3 += hp[12]*wD.x + hp[13]*wD.y + hp[14]*wD.z + hp[15]*wD.w;
            }
            fcat[r][g] = fmaxf(b2s[g] + (a0+a1) + (a2+a3), 0.f);
        }
    }
    __syncthreads();

    // ---- fts_X: fX[ri][c] = sum_j X[pt][i][j] * fcat[pt*16+j][c] ----
    const int ri = tid >> 3, cg = tid & 7;     // 32 rows x 8 col-groups
    const int pt = ri >> 4, i = ri & 15;
    float facc[16];
    {
        float xrow[16];
        #pragma unroll
        for (int jj = 0; jj < 16; jj += 4)
            *(float4*)&xrow[jj] = *(const float4*)&X3l[pt][i*16 + jj];
        #pragma unroll
        for (int a = 0; a < 16; ++a) facc[a] = 0.f;
        #pragma unroll
        for (int j = 0; j < 16; ++j) {
            float xv = xrow[j];
            const float* frow = &fcat[pt*16 + j][0];
            #pragma unroll
            for (int t = 0; t < 4; ++t) {      // c = cg*4 + t*32: conflict-free
                float4 v = *(const float4*)(frow + cg*4 + t*32);
                facc[t*4+0] += xv*v.x; facc[t*4+1] += xv*v.y;
                facc[t*4+2] += xv*v.z; facc[t*4+3] += xv*v.w;
            }
        }
    }
    __syncthreads();                            // all fcat reads done
    #pragma unroll
    for (int t = 0; t < 4; ++t)                 // overlay fX into fcat buffer
        *(float4*)&fcat[ri][cg*4 + t*32] =
            make_float4(facc[t*4+0], facc[t*4+1], facc[t*4+2], facc[t*4+3]);
    __syncthreads();

    // ---- depthwise: dw[pt][c*4+m] = b + sum_k fX[pt*16+k][c]*Wdw[c][m][k] ----
    {
        const int c = tid & 127, ptw = tid >> 7;
        float wv[64];
        #pragma unroll
        for (int i4 = 0; i4 < 16; ++i4)
            *(float4*)&wv[i4*4] = *(const float4*)(Wdw + c*64 + i4*4);
        float a0 = bdw[c*4+0], a1 = bdw[c*4+1], a2 = bdw[c*4+2], a3 = bdw[c*4+3];
        #pragma unroll
        for (int k = 0; k < 16; ++k) {
            float fv = fcat[ptw*16 + k][c];
            a0 += fv*wv[k]; a1 += fv*wv[16+k]; a2 += fv*wv[32+k]; a3 += fv*wv[48+k];
        }
        *(float4*)(dwout + (size_t)(pbase + ptw)*512 + c*4) = make_float4(a0,a1,a2,a3);
    }
}

// ---------------- Kernel C: pointwise GEMM ----------------
// 16 points/block, 1024 blocks. y[q][o] = b_pw[o] + dwf[q][:] . Wpw[o][:]
__global__ __launch_bounds__(256) void kC_pw(
    const float* __restrict__ dwf, const float* __restrict__ Wpw,
    const float* __restrict__ bpw, float* __restrict__ yout)
{
    __shared__ __align__(16) float dtile[16][512];   // 32 KB
    const int tid = threadIdx.x;
    const int o = tid & 127;
    const int pg = tid >> 7;                         // 2 groups of 8 points
    const int base = blockIdx.x * 16;

    #pragma unroll
    for (int it = 0; it < 8; ++it) {                 // 2048 float4, coalesced
        int idx = tid + it*256;
        int row = idx >> 7, c4 = (idx & 127) << 2;
        *(float4*)&dtile[row][c4] = *(const float4*)(dwf + (size_t)(base+row)*512 + c4);
    }
    __syncthreads();

    float acc[8];
    #pragma unroll
    for (int i = 0; i < 8; ++i) acc[i] = 0.f;

    #pragma unroll 4
    for (int j4 = 0; j4 < 128; ++j4) {
        float4 w = *(const float4*)(Wpw + (size_t)o*512 + j4*4);
        #pragma unroll
        for (int p = 0; p < 8; ++p) {                // broadcast LDS reads
            float4 d = *(const float4*)&dtile[pg*8 + p][j4*4];
            acc[p] += w.x*d.x + w.y*d.y + w.z*d.z + w.w*d.w;
        }
    }
    const float b = bpw[o];
    #pragma unroll
    for (int p = 0; p < 8; ++p)
        yout[(size_t)(base + pg*8 + p)*128 + o] = acc[p] + b;   // coalesced
}

// ---------------- Kernel Z: zero the stat accumulators ----------------
__global__ void kZ_zero(float* __restrict__ acc) {
    acc[threadIdx.x] = 0.f;    // 256 floats: accS[128] + accS2[128]
}

// ---------------- Kernel D1: per-block partial BN stats ----------------
__global__ __launch_bounds__(256) void kD1_part(
    const float* __restrict__ y, float* __restrict__ accS, float* __restrict__ accS2)
{
    __shared__ float sL[8][128], s2L[8][128];
    const int tid = threadIdx.x;
    const int rg = tid >> 5, cl = tid & 31;
    const int base = blockIdx.x * 64;
    float4 s = make_float4(0,0,0,0), s2 = make_float4(0,0,0,0);
    #pragma unroll
    for (int rr = 0; rr < 8; ++rr) {
        float4 v = *(const float4*)(y + (size_t)(base + rg*8 + rr)*128 + cl*4);
        s.x += v.x; s.y += v.y; s.z += v.z; s.w += v.w;
        s2.x += v.x*v.x; s2.y += v.y*v.y; s2.z += v.z*v.z; s2.w += v.w*v.w;
    }
    *(float4*)&sL[rg][cl*4] = s;
    *(float4*)&s2L[rg][cl*4] = s2;
    __syncthreads();
    if (tid < 128) {
        float a = 0.f, b = 0.f;
        #pragma unroll
        for (int g = 0; g < 8; ++g) { a += sL[g][tid]; b += s2L[g][tid]; }
        atomicAdd(accS + tid, a);
        atomicAdd(accS2 + tid, b);
    }
}

// ---------------- Kernel D2: finalize scale/shift ----------------
__global__ void kD2_fin(
    const float* __restrict__ accS, const float* __restrict__ accS2,
    const float* __restrict__ gamma, const float* __restrict__ beta,
    float* __restrict__ st)
{
    const int c = threadIdx.x;   // 128
    float mean = accS[c] * (1.f/NPTS);
    float var  = accS2[c] * (1.f/NPTS) - mean*mean;
    float rstd = rsqrtf(var + 1e-5f);
    float sc = gamma[c] * rstd;
    st[c] = sc;
    st[128 + c] = beta[c] - mean*sc;
}

// ---------------- Kernel E: normalize + relu ----------------
__global__ __launch_bounds__(256) void kE_final(
    const float* __restrict__ y, const float* __restrict__ st,
    float* __restrict__ out)
{
    const int idx = blockIdx.x*256 + threadIdx.x;   // float4 index
    float4 v = ((const float4*)y)[idx];
    int o0 = (idx & 31) << 2;
    float4 sc = *(const float4*)(st + o0);
    float4 sh = *(const float4*)(st + 128 + o0);
    float4 r;
    r.x = fmaxf(v.x*sc.x + sh.x, 0.f);
    r.y = fmaxf(v.y*sc.y + sh.y, 0.f);
    r.z = fmaxf(v.z*sc.z + sh.z, 0.f);
    r.w = fmaxf(v.w*sc.w + sh.w, 0.f);
    ((float4*)out)[idx] = r;
}

extern "C" void kernel_launch(void* const* d_in, const int* in_sizes, int n_in,
                              void* d_out, int out_size, void* d_ws, size_t ws_size,
                              hipStream_t stream) {
    const float* rep  = (const float*)d_in[0];
    const float* pts  = (const float*)d_in[1];
    const float* fts  = (const float*)d_in[2];
    const float* Wf1  = (const float*)d_in[3];
    const float* bf1  = (const float*)d_in[4];
    const float* Wf2  = (const float*)d_in[5];
    const float* bf2  = (const float*)d_in[6];
    const float* Wxc  = (const float*)d_in[7];
    const float* bxc  = (const float*)d_in[8];
    const float* Wx1  = (const float*)d_in[9];
    const float* bx1  = (const float*)d_in[10];
    const float* Wx2  = (const float*)d_in[11];
    const float* bx2  = (const float*)d_in[12];
    const float* Wdw  = (const float*)d_in[13];
    const float* bdw  = (const float*)d_in[14];
    const float* Wpw  = (const float*)d_in[15];
    const float* bpw  = (const float*)d_in[16];
    const float* gam  = (const float*)d_in[17];
    const float* bet  = (const float*)d_in[18];

    float* ws  = (float*)d_ws;
    float* X3  = ws;                                  // 16384*256
    float* dwf = X3 + (size_t)NPTS*256;               // 16384*512
    float* y   = dwf + (size_t)NPTS*512;              // 16384*128
    float* st  = y + (size_t)NPTS*128;                // 256
    float* acc = st + 256;                            // 256 (accS|accS2)

    kZ_zero<<<1, 256, 0, stream>>>(acc);
    kA_xchain<<<NPTS/16, 256, 0, stream>>>(rep, pts, Wxc, bxc, Wx1, bx1, Wx2, bx2, X3);
    kB_fused<<<NPTS/2, 256, 0, stream>>>(rep, pts, fts, Wf1, bf1, Wf2, bf2, Wdw, bdw, X3, dwf);
    kC_pw<<<NPTS/16, 256, 0, stream>>>(dwf, Wpw, bpw, y);
    kD1_part<<<NPTS/64, 256, 0, stream>>>(y, acc, acc + 128);
    kD2_fin<<<1, 128, 0, stream>>>(acc, acc + 128, gam, bet, st);
    kE_final<<<(NPTS*128/4)/256, 256, 0, stream>>>(y, st, (float*)d_out);
}

// Round 3
// 179.511 us; speedup vs baseline: 4.5039x; 1.8563x over previous
//
#include <hip/hip_runtime.h>

// XConv bf16-MFMA pipeline. N=16, P=1024, K=16, D=3, Cf=64, Fin=64,
// Ccat=128, DM=4, Cout=128. NPTS=16384 points, 262144 rows.
//
// MFMA conventions (mfma_f32_16x16x32_bf16, m89-verified):
//  A-frag: lane&15 = M-row, k = (lane>>4)*8 + [0..7]  (8 contiguous bf16)
//  B-frag: lane&15 = N-col, k = (lane>>4)*8 + [0..7]  (weights stored [N][K])
//  D:      col = lane&15, row = (lane>>4)*4 + reg

#define NPTS 16384

typedef short  s16x8 __attribute__((ext_vector_type(8)));
typedef float  f32x4 __attribute__((ext_vector_type(4)));

__device__ inline unsigned short f2b(float f) {
    unsigned u = __builtin_bit_cast(unsigned, f);
    unsigned r = u + 0x7FFF + ((u >> 16) & 1);
    return (unsigned short)(r >> 16);
}

#define MFMA(a,b,c) __builtin_amdgcn_mfma_f32_16x16x32_bf16((a),(b),(c),0,0,0)

// ---------------- kW: convert weights to bf16 (B^T layouts) ----------------
__global__ __launch_bounds__(256) void kW_cvt(
    const float* __restrict__ Wxc, const float* __restrict__ Wx1,
    const float* __restrict__ Wx2, const float* __restrict__ Wf2,
    const float* __restrict__ Wpw, unsigned short* __restrict__ Wb)
{
    unsigned short* Wxcb = Wb;            // [256][64] (K 48->64 zero-pad)
    unsigned short* Wx1b = Wxcb + 16384;  // [256][256]
    unsigned short* Wx2b = Wx1b + 65536;  // [256][256]
    unsigned short* Wf2b = Wx2b + 65536;  // [64][64]
    unsigned short* Wpwb = Wf2b + 4096;   // [128][512]
    int idx = blockIdx.x * 256 + threadIdx.x;
    if (idx < 16384) { int o = idx >> 6, j = idx & 63;
        Wxcb[idx] = (j < 48) ? f2b(Wxc[o*48 + j]) : 0; return; }
    idx -= 16384;
    if (idx < 65536) { Wx1b[idx] = f2b(Wx1[idx]); return; }
    idx -= 65536;
    if (idx < 65536) { Wx2b[idx] = f2b(Wx2[idx]); return; }
    idx -= 65536;
    if (idx < 4096)  { Wf2b[idx] = f2b(Wf2[idx]); return; }
    idx -= 4096;
    if (idx < 65536) { Wpwb[idx] = f2b(Wpw[idx]); return; }
}

// ---------------- kA: X-chain as 3 chained MFMA GEMMs ----------------
// 16 points/block, 256 thr = 4 waves; wave w owns output cols 64w..64w+63.
#define SA 72     // ptsl stride (bf16) — slot-uniform b128 reads
#define SX 264    // X1s/X2s stride
__global__ __launch_bounds__(256) void kA_mfma(
    const float* __restrict__ rep, const float* __restrict__ pts,
    const unsigned short* __restrict__ Wxcb, const float* __restrict__ bxc,
    const unsigned short* __restrict__ Wx1b, const float* __restrict__ bx1,
    const unsigned short* __restrict__ Wx2b, const float* __restrict__ bx2,
    unsigned short* __restrict__ X3b)
{
    __shared__ __align__(16) unsigned short pA[16*SA];
    __shared__ __align__(16) unsigned short X1s[16*SX];
    __shared__ __align__(16) unsigned short X2s[16*SX];
    const int tid = threadIdx.x;
    const int w = tid >> 6, lane = tid & 63, cl = lane & 15, lg = lane >> 4;
    const int base = blockIdx.x * 16;

    for (int idx = tid; idx < 1024; idx += 256) {     // stage local coords
        int pt = idx >> 6, j = idx & 63;
        float v = 0.f;
        if (j < 48) { int d = j >> 4, kk = j & 15;
            v = pts[(size_t)((base+pt)*16 + kk)*3 + d] - rep[(base+pt)*3 + d]; }
        pA[pt*SA + j] = f2b(v);
    }
    __syncthreads();

    f32x4 z = {0.f,0.f,0.f,0.f};
    {   // phase 1: X1 = relu(ptsl @ Wxc^T + b), K=48(->64)
        f32x4 acc[4] = {z,z,z,z};
        #pragma unroll
        for (int ks = 0; ks < 2; ++ks) {
            s16x8 a = *(const s16x8*)&pA[cl*SA + ks*32 + lg*8];
            #pragma unroll
            for (int ct = 0; ct < 4; ++ct) {
                int o = w*64 + ct*16 + cl;
                s16x8 b = *(const s16x8*)&Wxcb[o*64 + ks*32 + lg*8];
                acc[ct] = MFMA(a, b, acc[ct]);
            }
        }
        #pragma unroll
        for (int ct = 0; ct < 4; ++ct) {
            int o = w*64 + ct*16 + cl;
            float bias = bxc[o];
            #pragma unroll
            for (int r = 0; r < 4; ++r)
                X1s[(lg*4 + r)*SX + o] = f2b(fmaxf(acc[ct][r] + bias, 0.f));
        }
    }
    __syncthreads();

    {   // phase 2: X2 = relu(X1 @ Wx1^T + b), K=256
        f32x4 acc[4] = {z,z,z,z};
        #pragma unroll
        for (int ks = 0; ks < 8; ++ks) {
            s16x8 a = *(const s16x8*)&X1s[cl*SX + ks*32 + lg*8];
            #pragma unroll
            for (int ct = 0; ct < 4; ++ct) {
                int o = w*64 + ct*16 + cl;
                s16x8 b = *(const s16x8*)&Wx1b[(size_t)o*256 + ks*32 + lg*8];
                acc[ct] = MFMA(a, b, acc[ct]);
            }
        }
        #pragma unroll
        for (int ct = 0; ct < 4; ++ct) {
            int o = w*64 + ct*16 + cl;
            float bias = bx1[o];
            #pragma unroll
            for (int r = 0; r < 4; ++r)
                X2s[(lg*4 + r)*SX + o] = f2b(fmaxf(acc[ct][r] + bias, 0.f));
        }
    }
    __syncthreads();

    {   // phase 3: X3 = X2 @ Wx2^T + b (linear) -> global bf16 [p][256]
        f32x4 acc[4] = {z,z,z,z};
        #pragma unroll
        for (int ks = 0; ks < 8; ++ks) {
            s16x8 a = *(const s16x8*)&X2s[cl*SX + ks*32 + lg*8];
            #pragma unroll
            for (int ct = 0; ct < 4; ++ct) {
                int o = w*64 + ct*16 + cl;
                s16x8 b = *(const s16x8*)&Wx2b[(size_t)o*256 + ks*32 + lg*8];
                acc[ct] = MFMA(a, b, acc[ct]);
            }
        }
        #pragma unroll
        for (int ct = 0; ct < 4; ++ct) {
            int o = w*64 + ct*16 + cl;
            float bias = bx2[o];
            #pragma unroll
            for (int r = 0; r < 4; ++r)
                X3b[(size_t)(base + lg*4 + r)*256 + o] = f2b(acc[ct][r] + bias);
        }
    }
}

// ---------------- kB: lift(FC1 VALU + FC2 MFMA) + fts_X MFMA + depthwise ----------------
// 4 points/block (64 rows), 256 thr = 4 waves; wave w owns point w.
#define STRH 72
#define STRT 72   // fcatT stride; data region = first 128 B/row, XOR-swizzled 16B slots
__global__ __launch_bounds__(256) void kB_mfma(
    const float* __restrict__ rep, const float* __restrict__ pts,
    const float* __restrict__ fts,
    const float* __restrict__ Wf1, const float* __restrict__ bf1,
    const unsigned short* __restrict__ Wf2b, const float* __restrict__ bf2,
    const float* __restrict__ Wdw, const float* __restrict__ bdw,
    const unsigned short* __restrict__ X3b, unsigned short* __restrict__ dwb)
{
    __shared__ __align__(16) unsigned short hs[64*STRH];
    __shared__ __align__(16) unsigned short fcT[128*STRT];  // [c][rowlocal], swizzled
    __shared__ __align__(16) unsigned short Xf[4*4*16*8];   // [p][kb][i][8], k>=16 zero
    const int tid = threadIdx.x;
    const int w = tid >> 6, lane = tid & 63, cl = lane & 15, lg = lane >> 4;
    const int pbase = blockIdx.x * 4;
    const int rbase = pbase * 16;

    // phase 0a: FC1 -> hs (row = tid>>2 owns 16 feats)
    {
        const int r = tid >> 2, fg = tid & 3;
        const int row = rbase + r, q = row >> 4;
        float x0 = pts[(size_t)row*3+0] - rep[q*3+0];
        float x1 = pts[(size_t)row*3+1] - rep[q*3+1];
        float x2 = pts[(size_t)row*3+2] - rep[q*3+2];
        unsigned short hv[16];
        #pragma unroll
        for (int ff = 0; ff < 16; ++ff) {
            int f = fg*16 + ff;
            float h = fmaxf(bf1[f] + Wf1[f*3]*x0 + Wf1[f*3+1]*x1 + Wf1[f*3+2]*x2, 0.f);
            hv[ff] = f2b(h);
        }
        #pragma unroll
        for (int k4 = 0; k4 < 4; ++k4) {
            ushort4 pk; pk.x = hv[k4*4]; pk.y = hv[k4*4+1]; pk.z = hv[k4*4+2]; pk.w = hv[k4*4+3];
            *(ushort4*)&hs[r*STRH + fg*16 + k4*4] = pk;
        }
    }
    // phase 0b: X3 -> Xf frag-major, zero-pad K 16->32
    {
        int i = tid & 15, kb = (tid >> 4) & 3, p = tid >> 6;
        s16x8 v = {0,0,0,0,0,0,0,0};
        if (kb < 2) v = *(const s16x8*)&X3b[(size_t)(pbase + p)*256 + i*16 + kb*8];
        *(s16x8*)&Xf[((p*4 + kb)*16 + i)*8] = v;
    }
    // phase 0c: fts -> fcT[64+c][row] transposed, swizzled
    #pragma unroll
    for (int it = 0; it < 4; ++it) {
        int r = (tid >> 4) + it*16;          // local row 0..63
        int c0 = (tid & 15) * 4;
        float4 v = *(const float4*)&fts[(size_t)(rbase + r)*64 + c0];
        float vv[4] = {v.x, v.y, v.z, v.w};
        #pragma unroll
        for (int cc = 0; cc < 4; ++cc) {
            int c = 64 + c0 + cc;
            int wb = ((((r >> 3) ^ (c & 7)) << 4) | ((r & 7) * 2));
            *(unsigned short*)((char*)&fcT[c*STRT] + wb) = f2b(vv[cc]);
        }
    }
    __syncthreads();

    f32x4 z = {0.f,0.f,0.f,0.f};
    // phase 1: FC2 MFMA (M=64 rows, N=64, K=64) -> fcT[c][row] swizzled
    {
        f32x4 acc[4] = {z,z,z,z};
        #pragma unroll
        for (int ks = 0; ks < 2; ++ks) {
            s16x8 a = *(const s16x8*)&hs[(w*16 + cl)*STRH + ks*32 + lg*8];
            #pragma unroll
            for (int ct = 0; ct < 4; ++ct) {
                s16x8 b = *(const s16x8*)&Wf2b[(ct*16 + cl)*64 + ks*32 + lg*8];
                acc[ct] = MFMA(a, b, acc[ct]);
            }
        }
        #pragma unroll
        for (int ct = 0; ct < 4; ++ct) {
            int c = ct*16 + cl;
            float bias = bf2[c];
            int r0 = w*16 + lg*4;
            ushort4 pk;
            pk.x = f2b(fmaxf(acc[ct][0] + bias, 0.f));
            pk.y = f2b(fmaxf(acc[ct][1] + bias, 0.f));
            pk.z = f2b(fmaxf(acc[ct][2] + bias, 0.f));
            pk.w = f2b(fmaxf(acc[ct][3] + bias, 0.f));
            int wb = ((((r0 >> 3) ^ (c & 7)) << 4) | ((r0 & 7) * 2));
            *(ushort4*)((char*)&fcT[c*STRT] + wb) = pk;
        }
    }
    __syncthreads();

    // phase 2: fts_X per point (A = Xp 16x16 zero-padded to K=32, B = fcatT)
    f32x4 fx[8] = {z,z,z,z,z,z,z,z};
    {
        s16x8 a = *(const s16x8*)&Xf[((w*4 + lg)*16 + cl)*8];
        #pragma unroll
        for (int ct = 0; ct < 8; ++ct) {
            int c = ct*16 + cl;
            int slot = ((2*w + lg) & 7) ^ (c & 7);   // lg>=2 reads garbage (A=0 there)
            s16x8 b = *(const s16x8*)((const char*)&fcT[c*STRT] + (slot << 4));
            fx[ct] = MFMA(a, b, fx[ct]);
        }
    }

    // phase 3: depthwise + bias -> dwb bf16 [p][512]
    #pragma unroll
    for (int ct = 0; ct < 8; ++ct) {
        int c = ct*16 + cl;
        float om[4];
        #pragma unroll
        for (int m = 0; m < 4; ++m) {
            float4 wv = *(const float4*)&Wdw[(size_t)(c*4 + m)*16 + lg*4];
            float s = fx[ct][0]*wv.x + fx[ct][1]*wv.y + fx[ct][2]*wv.z + fx[ct][3]*wv.w;
            s += __shfl_xor(s, 16);
            s += __shfl_xor(s, 32);
            om[m] = s + bdw[c*4 + m];
        }
        if (lg == 0) {
            ushort4 pk; pk.x = f2b(om[0]); pk.y = f2b(om[1]); pk.z = f2b(om[2]); pk.w = f2b(om[3]);
            *(ushort4*)&dwb[(size_t)(pbase + w)*512 + c*4] = pk;
        }
    }
}

// ---------------- kC: pointwise MFMA GEMM (M=16384, N=128, K=512) ----------------
// 32 points/block; wave: mt = w&1 (16 rows), n-half = w>>1 (4 col-tiles).
__global__ __launch_bounds__(256) void kC_mfma(
    const unsigned short* __restrict__ dwb, const unsigned short* __restrict__ Wpwb,
    const float* __restrict__ bpw, float* __restrict__ y)
{
    const int tid = threadIdx.x;
    const int w = tid >> 6, lane = tid & 63, cl = lane & 15, lg = lane >> 4;
    const int m0 = blockIdx.x*32 + (w & 1)*16;
    const int nh = w >> 1;
    f32x4 z = {0.f,0.f,0.f,0.f};
    f32x4 acc[4] = {z,z,z,z};
    for (int ks = 0; ks < 16; ++ks) {
        s16x8 a = *(const s16x8*)&dwb[(size_t)(m0 + cl)*512 + ks*32 + lg*8];
        #pragma unroll
        for (int ct = 0; ct < 4; ++ct) {
            int o = nh*64 + ct*16 + cl;
            s16x8 b = *(const s16x8*)&Wpwb[(size_t)o*512 + ks*32 + lg*8];
            acc[ct] = MFMA(a, b, acc[ct]);
        }
    }
    #pragma unroll
    for (int ct = 0; ct < 4; ++ct) {
        int o = nh*64 + ct*16 + cl;
        float bias = bpw[o];
        #pragma unroll
        for (int r = 0; r < 4; ++r)
            y[(size_t)(m0 + lg*4 + r)*128 + o] = acc[ct][r] + bias;
    }
}

// ---------------- kZ / kD1 / kD2 / kE: BN + relu (unchanged) ----------------
__global__ void kZ_zero(float* __restrict__ acc) { acc[threadIdx.x] = 0.f; }

__global__ __launch_bounds__(256) void kD1_part(
    const float* __restrict__ y, float* __restrict__ accS, float* __restrict__ accS2)
{
    __shared__ float sL[8][128], s2L[8][128];
    const int tid = threadIdx.x;
    const int rg = tid >> 5, clx = tid & 31;
    const int base = blockIdx.x * 64;
    float4 s = make_float4(0,0,0,0), s2 = make_float4(0,0,0,0);
    #pragma unroll
    for (int rr = 0; rr < 8; ++rr) {
        float4 v = *(const float4*)(y + (size_t)(base + rg*8 + rr)*128 + clx*4);
        s.x += v.x; s.y += v.y; s.z += v.z; s.w += v.w;
        s2.x += v.x*v.x; s2.y += v.y*v.y; s2.z += v.z*v.z; s2.w += v.w*v.w;
    }
    *(float4*)&sL[rg][clx*4] = s;
    *(float4*)&s2L[rg][clx*4] = s2;
    __syncthreads();
    if (tid < 128) {
        float a = 0.f, b = 0.f;
        #pragma unroll
        for (int g = 0; g < 8; ++g) { a += sL[g][tid]; b += s2L[g][tid]; }
        atomicAdd(accS + tid, a);
        atomicAdd(accS2 + tid, b);
    }
}

__global__ void kD2_fin(
    const float* __restrict__ accS, const float* __restrict__ accS2,
    const float* __restrict__ gamma, const float* __restrict__ beta,
    float* __restrict__ st)
{
    const int c = threadIdx.x;
    float mean = accS[c] * (1.f/NPTS);
    float var  = accS2[c] * (1.f/NPTS) - mean*mean;
    float rstd = rsqrtf(var + 1e-5f);
    float sc = gamma[c] * rstd;
    st[c] = sc;
    st[128 + c] = beta[c] - mean*sc;
}

__global__ __launch_bounds__(256) void kE_final(
    const float* __restrict__ y, const float* __restrict__ st,
    float* __restrict__ out)
{
    const int idx = blockIdx.x*256 + threadIdx.x;
    float4 v = ((const float4*)y)[idx];
    int o0 = (idx & 31) << 2;
    float4 sc = *(const float4*)(st + o0);
    float4 sh = *(const float4*)(st + 128 + o0);
    float4 r;
    r.x = fmaxf(v.x*sc.x + sh.x, 0.f);
    r.y = fmaxf(v.y*sc.y + sh.y, 0.f);
    r.z = fmaxf(v.z*sc.z + sh.z, 0.f);
    r.w = fmaxf(v.w*sc.w + sh.w, 0.f);
    ((float4*)out)[idx] = r;
}

extern "C" void kernel_launch(void* const* d_in, const int* in_sizes, int n_in,
                              void* d_out, int out_size, void* d_ws, size_t ws_size,
                              hipStream_t stream) {
    const float* rep  = (const float*)d_in[0];
    const float* pts  = (const float*)d_in[1];
    const float* fts  = (const float*)d_in[2];
    const float* Wf1  = (const float*)d_in[3];
    const float* bf1  = (const float*)d_in[4];
    const float* Wf2  = (const float*)d_in[5];
    const float* bf2  = (const float*)d_in[6];
    const float* Wxc  = (const float*)d_in[7];
    const float* bxc  = (const float*)d_in[8];
    const float* Wx1  = (const float*)d_in[9];
    const float* bx1  = (const float*)d_in[10];
    const float* Wx2  = (const float*)d_in[11];
    const float* bx2  = (const float*)d_in[12];
    const float* Wdw  = (const float*)d_in[13];
    const float* bdw  = (const float*)d_in[14];
    const float* Wpw  = (const float*)d_in[15];
    const float* bpw  = (const float*)d_in[16];
    const float* gam  = (const float*)d_in[17];
    const float* bet  = (const float*)d_in[18];

    unsigned short* X3b = (unsigned short*)d_ws;                 // 16384*256 bf16
    unsigned short* dwb = X3b + (size_t)NPTS*256;                // 16384*512 bf16
    float* y   = (float*)(dwb + (size_t)NPTS*512);               // 16384*128 f32
    float* st  = y + (size_t)NPTS*128;                           // 256
    float* acc = st + 256;                                       // 256
    unsigned short* Wb = (unsigned short*)(acc + 256);           // 217088 bf16
    unsigned short* Wxcb = Wb;
    unsigned short* Wx1b = Wxcb + 16384;
    unsigned short* Wx2b = Wx1b + 65536;
    unsigned short* Wf2b = Wx2b + 65536;
    unsigned short* Wpwb = Wf2b + 4096;

    kZ_zero<<<1, 256, 0, stream>>>(acc);
    kW_cvt<<<848, 256, 0, stream>>>(Wxc, Wx1, Wx2, Wf2, Wpw, Wb);
    kA_mfma<<<NPTS/16, 256, 0, stream>>>(rep, pts, Wxcb, bxc, Wx1b, bx1, Wx2b, bx2, X3b);
    kB_mfma<<<NPTS/4, 256, 0, stream>>>(rep, pts, fts, Wf1, bf1, Wf2b, bf2, Wdw, bdw, X3b, dwb);
    kC_mfma<<<NPTS/32, 256, 0, stream>>>(dwb, Wpwb, bpw, y);
    kD1_part<<<NPTS/64, 256, 0, stream>>>(y, acc, acc + 128);
    kD2_fin<<<1, 128, 0, stream>>>(acc, acc + 128, gam, bet, st);
    kE_final<<<(NPTS*128/4)/256, 256, 0, stream>>>(y, st, (float*)d_out);
}